// Round 8
// baseline (657.762 us; speedup 1.0000x reference)
//
#include <hip/hip_runtime.h>
#include <math.h>
#include <stdint.h>

// Problem constants (FPModule: knn-interpolate + 2-layer MLP)
#define Bn    4
#define Nn    2048
#define Mn    8192
#define CIN   256
#define CSKIP 128
#define HID   256
#define COUT  128
#define KTOT  384   // CIN + CSKIP

// spatial grid
#define GC    8                 // cells per axis
#define NC    512               // GC^3
#define GLO   -5.0f
#define GH    1.25f             // cell size ([-5,5] span)

typedef short bf16x8 __attribute__((ext_vector_type(8)));
typedef float f32x16 __attribute__((ext_vector_type(16)));

__device__ __forceinline__ ushort f2bf(float f) {
    union { float f; unsigned u; } v; v.f = f;
    return (ushort)((v.u + 0x7fffu + ((v.u >> 16) & 1u)) >> 16);   // RNE
}

// 5-op sorted-insert of key k into (kA <= kB <= kC), keeping 3 smallest.
// Order-independent: final triple = 3 smallest keys of the inserted set.
#define INSERT3(kA, kB, kC, k)            \
    do {                                  \
        const double _t = fmax(kA, k);    \
        kA = fmin(kA, k);                 \
        const double _u = fmax(kB, _t);   \
        kB = fmin(kB, _t);                \
        kC = fmin(kC, _u);                \
    } while (0)

__device__ __forceinline__ int cellof(float v) {
    int c = (int)floorf((v - GLO) / GH);
    return min(max(c, 0), GC - 1);
}

// ---------------------------------------------------------------------------
// Kernel A: per-batch grid build. One block per batch (4 blocks x 512 thr).
// LDS histogram -> serial prefix (thread 0, 512 adds, trivial) -> scatter.
// Scattered pos4 = (2px,2py,2pz,pp): pp via explicit _rn ops; 2x exact, so
// the query-side dot2 is bit-identical to 2*dot of the reference.
// sidx keeps the ORIGINAL point index (tie-break + feature gather).
// ---------------------------------------------------------------------------
__global__ __launch_bounds__(512) void build_grid(
    const float* __restrict__ pos,       // (B*N, 3)
    float4* __restrict__ spos4,          // (B*N) cell-sorted
    int*    __restrict__ sidx,           // (B*N) original index
    int*    __restrict__ cellStart)      // (B, NC+1)
{
    __shared__ int hist[NC];
    __shared__ int cstart[NC + 1];
    __shared__ int cnt[NC];

    const int b = blockIdx.x, tid = threadIdx.x;
    for (int c = tid; c < NC; c += 512) { hist[c] = 0; cnt[c] = 0; }
    __syncthreads();

    int cellv[4];
#pragma unroll
    for (int t = 0; t < 4; ++t) {
        const int i = tid * 4 + t;                 // 0..2047
        const float* p = pos + ((size_t)b * Nn + i) * 3;
        const int cx = cellof(p[0]), cy = cellof(p[1]), cz = cellof(p[2]);
        const int cell = (cz * GC + cy) * GC + cx;
        cellv[t] = cell;
        atomicAdd(&hist[cell], 1);
    }
    __syncthreads();

    if (tid == 0) {
        int acc = 0;
        for (int c = 0; c < NC; ++c) { cstart[c] = acc; acc += hist[c]; }
        cstart[NC] = acc;                          // == Nn
    }
    __syncthreads();

#pragma unroll
    for (int t = 0; t < 4; ++t) {
        const int i = tid * 4 + t;
        const float* p = pos + ((size_t)b * Nn + i) * 3;
        const float p0 = p[0], p1 = p[1], p2 = p[2];
        const float pp = __fadd_rn(__fadd_rn(__fmul_rn(p0, p0), __fmul_rn(p1, p1)),
                                   __fmul_rn(p2, p2));
        const int slot = cstart[cellv[t]] + atomicAdd(&cnt[cellv[t]], 1);
        spos4[(size_t)b * Nn + slot] = make_float4(2.0f * p0, 2.0f * p1, 2.0f * p2, pp);
        sidx [(size_t)b * Nn + slot] = i;
    }
    __syncthreads();
    for (int c = tid; c <= NC; c += 512) cellStart[b * (NC + 1) + c] = cstart[c];
}

// ---------------------------------------------------------------------------
// Kernel B (fused mid): block roles by blockIdx.x:
//   [0,512)        KNN: 64 queries/block, 1 thread/query shell-scan select
//                  (threads 64..255 idle in phase 1), then 4-wave gather.
//   [512,4608)     Abig[:,256:384] = bf16(x_skip)
//   [4608,4704)    W1T[n][k] = bf16(W1[k][n])
//   [4704,4736)    W2T[n][k] = bf16(W2[k][n])
//   [4736,5248)    tail: copy pos_skip + synthesize batch_skip into d_out
//
// Selection correctness: d computed with the exact reference _rn sequence from
// spos4 (bit-identical to reference d2). f64 key = double(d) | orig_idx packs
// lex (d, idx) == top_k value-then-lowest-index order; INSERT3 keeps the 3
// smallest keys independent of scan order. Shell stop: after shell k, any
// unscanned point is >= rmin away (slab distance to scanned box; grid-edge
// sides open -> conservative for clamped outliers); stop only when
// d3 < rmin^2 - 0.01 (margin >> all f32 rounding) so the candidate set
// provably contains the reference top-3 incl. exact ties.
// ---------------------------------------------------------------------------
__global__ __launch_bounds__(256) void knn_gather(
    const float* __restrict__ x,          // (B*N, CIN)
    const float4* __restrict__ spos4,     // cell-sorted packed points
    const int*    __restrict__ sidx,      // original indices
    const int*    __restrict__ cellStart, // (B, NC+1)
    const float* __restrict__ xs,         // (B*M, CSKIP)
    const float* __restrict__ pos_skip,   // (B*M, 3)
    const float* __restrict__ W1, const float* __restrict__ W2,
    ushort* __restrict__ Abig,            // (B*M, KTOT) bf16
    ushort* __restrict__ W1T, ushort* __restrict__ W2T,
    float* __restrict__ tail_dst)         // d_out + B*M*COUT
{
    __shared__ int   sc[NC + 1];          // this batch's cell starts (2 KB)
    __shared__ int   rIdx[64][3];
    __shared__ float rW[64][3];           // premultiplied w_i/den

    const int bid = blockIdx.x;
    const int tid = threadIdx.x;

    if (bid >= 512) {
        // ---------------- aux roles ----------------
        const int cb = bid - 512;
        if (cb < 4096) {
            const int q   = cb * 256 + tid;        // quad over 32768x128
            const int row = q >> 5;
            const int cq  = (q & 31) * 4;
            const float4 v = *(const float4*)(xs + (size_t)row * CSKIP + cq);
            ushort4 o; o.x = f2bf(v.x); o.y = f2bf(v.y); o.z = f2bf(v.z); o.w = f2bf(v.w);
            *(ushort4*)(Abig + (size_t)row * KTOT + CIN + cq) = o;
        } else if (cb < 4192) {
            const int q  = (cb - 4096) * 256 + tid;   // 24576 quads: n*96 + kq
            const int n  = q / 96;
            const int kq = (q % 96) * 4;
            ushort4 o;
            o.x = f2bf(W1[(size_t)(kq + 0) * HID + n]);
            o.y = f2bf(W1[(size_t)(kq + 1) * HID + n]);
            o.z = f2bf(W1[(size_t)(kq + 2) * HID + n]);
            o.w = f2bf(W1[(size_t)(kq + 3) * HID + n]);
            *(ushort4*)(W1T + (size_t)n * KTOT + kq) = o;
        } else if (cb < 4224) {
            const int q  = (cb - 4192) * 256 + tid;   // 8192 quads: n*64 + kq
            const int n  = q >> 6;
            const int kq = (q & 63) * 4;
            ushort4 o;
            o.x = f2bf(W2[(size_t)(kq + 0) * COUT + n]);
            o.y = f2bf(W2[(size_t)(kq + 1) * COUT + n]);
            o.z = f2bf(W2[(size_t)(kq + 2) * COUT + n]);
            o.w = f2bf(W2[(size_t)(kq + 3) * COUT + n]);
            *(ushort4*)(W2T + (size_t)n * HID + kq) = o;
        } else {
            const int i = (cb - 4224) * 256 + tid;
            const int nPos = Bn * Mn * 3;             // 98304
            if (i < nPos) tail_dst[i] = pos_skip[i];
            else          tail_dst[i] = (float)((i - nPos) >> 13);
        }
        return;
    }

    // ---------------- KNN role ----------------
    const int blockQ = bid * 64;
    const int b      = blockQ / Mn;        // 128 blocks per batch

    for (int c = tid; c <= NC; c += 256) sc[c] = cellStart[b * (NC + 1) + c];
    __syncthreads();

    if (tid < 64) {
        const int q = blockQ + tid;
        const float* qp = pos_skip + (size_t)q * 3;
        const float q0 = qp[0], q1 = qp[1], q2 = qp[2];
        const float qq = __fadd_rn(__fadd_rn(__fmul_rn(q0, q0), __fmul_rn(q1, q1)),
                                   __fmul_rn(q2, q2));
        const int cx = cellof(q0), cy = cellof(q1), cz = cellof(q2);

        const float4* __restrict__ cp = spos4 + (size_t)b * Nn;
        const int*    __restrict__ ci = sidx  + (size_t)b * Nn;

        double kA = (double)INFINITY, kB = (double)INFINITY, kC = (double)INFINITY;

        for (int k = 0;; ++k) {
            const int zlo = max(cz - k, 0), zhi = min(cz + k, GC - 1);
            const int ylo = max(cy - k, 0), yhi = min(cy + k, GC - 1);
            const int xlo = max(cx - k, 0), xhi = min(cx + k, GC - 1);
            for (int z = zlo; z <= zhi; ++z)
                for (int y = ylo; y <= yhi; ++y)
                    for (int xx = xlo; xx <= xhi; ++xx) {
                        const int cheb = max(max(abs(xx - cx), abs(y - cy)), abs(z - cz));
                        if (cheb != k) continue;          // only the new shell
                        const int cell = (z * GC + y) * GC + xx;
                        const int en = sc[cell + 1];
                        for (int i = sc[cell]; i < en; ++i) {
                            const float4 P = cp[i];
                            const float dot2 = __fadd_rn(
                                __fadd_rn(__fmul_rn(q0, P.x), __fmul_rn(q1, P.y)),
                                __fmul_rn(q2, P.z));
                            const float d = __fsub_rn(__fadd_rn(qq, P.w), dot2);
                            const double kk = __longlong_as_double(
                                __double_as_longlong((double)d) | (long long)ci[i]);
                            INSERT3(kA, kB, kC, kk);
                        }
                    }
            if (k >= GC - 1) break;                      // whole grid scanned
            // stop check: slab distance from q to scanned-box boundary
            const float dC = (float)__longlong_as_double(
                __double_as_longlong(kC) & ~0x7FFll);    // INF if <3 found
            float rmin = 1e30f;
            if (cx - k > 0)      rmin = fminf(rmin, q0 - (GLO + (float)(cx - k) * GH));
            if (cx + k < GC - 1) rmin = fminf(rmin, (GLO + (float)(cx + k + 1) * GH) - q0);
            if (cy - k > 0)      rmin = fminf(rmin, q1 - (GLO + (float)(cy - k) * GH));
            if (cy + k < GC - 1) rmin = fminf(rmin, (GLO + (float)(cy + k + 1) * GH) - q1);
            if (cz - k > 0)      rmin = fminf(rmin, q2 - (GLO + (float)(cz - k) * GH));
            if (cz + k < GC - 1) rmin = fminf(rmin, (GLO + (float)(cz + k + 1) * GH) - q2);
            rmin = fmaxf(rmin, 0.0f);
            if (dC < rmin * rmin - 0.01f) break;
        }

        const long long ba = __double_as_longlong(kA);
        const long long bb = __double_as_longlong(kB);
        const long long bc = __double_as_longlong(kC);
        const float dA = (float)__longlong_as_double(ba & ~0x7FFll);
        const float dB = (float)__longlong_as_double(bb & ~0x7FFll);
        const float dC = (float)__longlong_as_double(bc & ~0x7FFll);
        const float w0 = 1.0f / (fmaxf(dA, 0.0f) + 1e-16f);
        const float w1 = 1.0f / (fmaxf(dB, 0.0f) + 1e-16f);
        const float w2 = 1.0f / (fmaxf(dC, 0.0f) + 1e-16f);
        const float rden = 1.0f / (w0 + w1 + w2);
        rIdx[tid][0] = (int)(ba & 0x7FF);
        rIdx[tid][1] = (int)(bb & 0x7FF);
        rIdx[tid][2] = (int)(bc & 0x7FF);
        rW[tid][0] = w0 * rden; rW[tid][1] = w1 * rden; rW[tid][2] = w2 * rden;
    }
    __syncthreads();

    // gather: wave w handles queries [w*16, w*16+16); lane covers 4 channels
    const int wave = tid >> 6, lane = tid & 63;
    const size_t xbase = (size_t)b * Nn * CIN;
    for (int j = 0; j < 16; ++j) {
        const int lq = wave * 16 + j;
        const int gq = blockQ + lq;
        const int i0 = rIdx[lq][0], i1 = rIdx[lq][1], i2 = rIdx[lq][2];
        const float w0 = rW[lq][0], w1 = rW[lq][1], w2 = rW[lq][2];
        const float4 f0 = ((const float4*)(x + xbase + (size_t)i0 * CIN))[lane];
        const float4 f1 = ((const float4*)(x + xbase + (size_t)i1 * CIN))[lane];
        const float4 f2 = ((const float4*)(x + xbase + (size_t)i2 * CIN))[lane];
        ushort4 ov;
        ov.x = f2bf(fmaf(w2, f2.x, fmaf(w1, f1.x, w0 * f0.x)));
        ov.y = f2bf(fmaf(w2, f2.y, fmaf(w1, f1.y, w0 * f0.y)));
        ov.z = f2bf(fmaf(w2, f2.z, fmaf(w1, f1.z, w0 * f0.z)));
        ov.w = f2bf(fmaf(w2, f2.w, fmaf(w1, f1.w, w0 * f0.w)));
        *(ushort4*)(Abig + (size_t)gq * KTOT + lane * 4) = ov;
    }
}

// ---------------------------------------------------------------------------
// Kernel C: fused MLP via bf16 MFMA (32x32x16), f32 accum. (unchanged)
// ---------------------------------------------------------------------------
__global__ __launch_bounds__(256, 1) void mlp_fused(
    const ushort* __restrict__ Abig,   // [32768][384] bf16
    const ushort* __restrict__ W1T,    // [256][384] bf16
    const float*  __restrict__ b1,
    const ushort* __restrict__ W2T,    // [128][256] bf16
    const float*  __restrict__ b2,
    float* __restrict__ out)           // [32768][128] f32
{
    __shared__ ushort Ast[128 * 32];   // 8 KB
    __shared__ ushort Bst[128 * 32];   // 8 KB
    __shared__ ushort Hs [128 * 128];  // 32 KB

    const int tid  = threadIdx.x;
    const int wave = tid >> 6, lane = tid & 63;
    const int wr = wave >> 1, wc = wave & 1;      // 2x2 wave grid
    const int l31 = lane & 31, kc0 = lane >> 5;   // MFMA k-half
    const long rowbase = (long)blockIdx.x * 128;

    const int sr0 = tid >> 2;          // staging row (row+64 for 2nd chunk)
    const int ss0 = tid & 3;           // 16B slot
    const int ssw = (ss0 ^ (sr0 & 3)); // swizzled slot

    f32x16 acc2[2][2];
#pragma unroll
    for (int i = 0; i < 2; ++i)
#pragma unroll
        for (int j = 0; j < 2; ++j)
#pragma unroll
            for (int e = 0; e < 16; ++e) acc2[i][j][e] = 0.0f;

    for (int nh = 0; nh < 2; ++nh) {
        f32x16 acc1[2][2];
#pragma unroll
        for (int i = 0; i < 2; ++i)
#pragma unroll
            for (int j = 0; j < 2; ++j)
#pragma unroll
                for (int e = 0; e < 16; ++e) acc1[i][j][e] = 0.0f;

        const ushort* Ab = Abig + (size_t)rowbase * KTOT;
        const ushort* Wb = W1T + (size_t)(nh * 128) * KTOT;

        uint4 ra0, ra1, rb0, rb1;
        ra0 = *(const uint4*)(Ab + (size_t)sr0 * KTOT + ss0 * 8);
        ra1 = *(const uint4*)(Ab + (size_t)(sr0 + 64) * KTOT + ss0 * 8);
        rb0 = *(const uint4*)(Wb + (size_t)sr0 * KTOT + ss0 * 8);
        rb1 = *(const uint4*)(Wb + (size_t)(sr0 + 64) * KTOT + ss0 * 8);

        for (int t = 0; t < 12; ++t) {
            __syncthreads();
            *(uint4*)&Ast[sr0 * 32 + (ssw << 3)]        = ra0;
            *(uint4*)&Ast[(sr0 + 64) * 32 + (ssw << 3)] = ra1;
            *(uint4*)&Bst[sr0 * 32 + (ssw << 3)]        = rb0;
            *(uint4*)&Bst[(sr0 + 64) * 32 + (ssw << 3)] = rb1;
            __syncthreads();
            if (t < 11) {
                const int kt = (t + 1) * 32;
                ra0 = *(const uint4*)(Ab + (size_t)sr0 * KTOT + kt + ss0 * 8);
                ra1 = *(const uint4*)(Ab + (size_t)(sr0 + 64) * KTOT + kt + ss0 * 8);
                rb0 = *(const uint4*)(Wb + (size_t)sr0 * KTOT + kt + ss0 * 8);
                rb1 = *(const uint4*)(Wb + (size_t)(sr0 + 64) * KTOT + kt + ss0 * 8);
            }
#pragma unroll
            for (int s = 0; s < 2; ++s) {
                bf16x8 af[2], bq[2];
#pragma unroll
                for (int mf = 0; mf < 2; ++mf) {
                    const int r = wr * 64 + mf * 32 + l31;
                    af[mf] = *(const bf16x8*)&Ast[r * 32 + ((((s << 1) | kc0) ^ (r & 3)) << 3)];
                }
#pragma unroll
                for (int nf = 0; nf < 2; ++nf) {
                    const int rn = wc * 64 + nf * 32 + l31;
                    bq[nf] = *(const bf16x8*)&Bst[rn * 32 + ((((s << 1) | kc0) ^ (rn & 3)) << 3)];
                }
#pragma unroll
                for (int mf = 0; mf < 2; ++mf)
#pragma unroll
                    for (int nf = 0; nf < 2; ++nf)
                        acc1[mf][nf] = __builtin_amdgcn_mfma_f32_32x32x16_bf16(
                            af[mf], bq[nf], acc1[mf][nf], 0, 0, 0);
            }
        }

#pragma unroll
        for (int mf = 0; mf < 2; ++mf)
#pragma unroll
            for (int nf = 0; nf < 2; ++nf) {
                const int col = wc * 64 + nf * 32 + l31;
                const float b1v = b1[nh * 128 + col];
#pragma unroll
                for (int e = 0; e < 16; ++e) {
                    const int rl = wr * 64 + mf * 32 + (e & 3) + ((e >> 2) << 3) + (kc0 << 2);
                    const float hv = fmaxf(acc1[mf][nf][e] + b1v, 0.0f);
                    Hs[rl * 128 + (((col >> 3) ^ (rl & 7)) << 3) + (col & 7)] = f2bf(hv);
                }
            }
        __syncthreads();

        uint4 rw0, rw1;
        rw0 = *(const uint4*)(W2T + (size_t)sr0 * HID + nh * 128 + ss0 * 8);
        rw1 = *(const uint4*)(W2T + (size_t)(sr0 + 64) * HID + nh * 128 + ss0 * 8);

        for (int t = 0; t < 4; ++t) {
            __syncthreads();
            *(uint4*)&Bst[sr0 * 32 + (ssw << 3)]        = rw0;
            *(uint4*)&Bst[(sr0 + 64) * 32 + (ssw << 3)] = rw1;
            __syncthreads();
            if (t < 3) {
                const int kt = nh * 128 + (t + 1) * 32;
                rw0 = *(const uint4*)(W2T + (size_t)sr0 * HID + kt + ss0 * 8);
                rw1 = *(const uint4*)(W2T + (size_t)(sr0 + 64) * HID + kt + ss0 * 8);
            }
#pragma unroll
            for (int s = 0; s < 2; ++s) {
                bf16x8 af[2], bq[2];
#pragma unroll
                for (int mf = 0; mf < 2; ++mf) {
                    const int r  = wr * 64 + mf * 32 + l31;
                    const int kc = (t << 2) + (s << 1) + kc0;
                    af[mf] = *(const bf16x8*)&Hs[r * 128 + ((kc ^ (r & 7)) << 3)];
                }
#pragma unroll
                for (int nf = 0; nf < 2; ++nf) {
                    const int rn = wc * 64 + nf * 32 + l31;
                    bq[nf] = *(const bf16x8*)&Bst[rn * 32 + ((((s << 1) | kc0) ^ (rn & 3)) << 3)];
                }
#pragma unroll
                for (int mf = 0; mf < 2; ++mf)
#pragma unroll
                    for (int nf = 0; nf < 2; ++nf)
                        acc2[mf][nf] = __builtin_amdgcn_mfma_f32_32x32x16_bf16(
                            af[mf], bq[nf], acc2[mf][nf], 0, 0, 0);
            }
        }
        __syncthreads();
    }

#pragma unroll
    for (int mf = 0; mf < 2; ++mf)
#pragma unroll
        for (int nf = 0; nf < 2; ++nf) {
            const int col = wc * 64 + nf * 32 + l31;
            const float b2v = b2[col];
#pragma unroll
            for (int e = 0; e < 16; ++e) {
                const int rl = wr * 64 + mf * 32 + (e & 3) + ((e >> 2) << 3) + (kc0 << 2);
                out[(rowbase + rl) * COUT + col] = acc2[mf][nf][e] + b2v;
            }
        }
}

// ---------------------------------------------------------------------------
extern "C" void kernel_launch(void* const* d_in, const int* in_sizes, int n_in,
                              void* d_out, int out_size, void* d_ws, size_t ws_size,
                              hipStream_t stream)
{
    const float* x        = (const float*)d_in[0];
    const float* pos      = (const float*)d_in[1];
    const float* x_skip   = (const float*)d_in[2];
    const float* pos_skip = (const float*)d_in[3];
    const float* W1       = (const float*)d_in[4];
    const float* b1       = (const float*)d_in[5];
    const float* W2       = (const float*)d_in[6];
    const float* b2       = (const float*)d_in[7];

    float* out = (float*)d_out;

    // workspace: Abig | W1T | W2T | spos4 | sidx | cellStart
    char* wp = (char*)d_ws;
    ushort* Abig = (ushort*)wp;  wp += (size_t)Bn * Mn * KTOT * 2;   // 24 MB
    ushort* W1T  = (ushort*)wp;  wp += (size_t)HID * KTOT * 2;       // 192 KB
    ushort* W2T  = (ushort*)wp;  wp += (size_t)COUT * HID * 2;       // 64 KB
    float4* spos4 = (float4*)wp; wp += (size_t)Bn * Nn * 16;         // 128 KB
    int*    sidx  = (int*)wp;    wp += (size_t)Bn * Nn * 4;          // 32 KB
    int*    cellS = (int*)wp;                                        // 8.2 KB

    // A) per-batch grid build (hist + prefix + scatter)
    build_grid<<<dim3(Bn), 512, 0, stream>>>(pos, spos4, sidx, cellS);

    // B) KNN shell-scan + gather (512 blocks) + converts + tail (4736 blocks)
    knn_gather<<<dim3(512 + 4736), 256, 0, stream>>>(
        x, spos4, sidx, cellS, x_skip, pos_skip, W1, W2, Abig, W1T, W2T,
        out + (size_t)Bn * Mn * COUT);

    // C) fused MLP: out = (relu([xi|x_skip] @ W1 + b1)) @ W2 + b2
    mlp_fused<<<dim3(Bn * Mn / 128), 256, 0, stream>>>(
        Abig, W1T, b1, W2T, b2, out);
}